// Round 7
// baseline (252.891 us; speedup 1.0000x reference)
//
#include <hip/hip_runtime.h>
#include <hip/hip_cooperative_groups.h>

namespace cg = cooperative_groups;

// GriddingDistance: fused cooperative binning + LDS privatization.
// Output: [pred_grid (8*G) | gt_grid (8*G)] fp32, G = 128^3.
//
// One cooperative kernel, 256 blocks x 1024 threads x 128 KiB LDS (1 block/CU):
//   phase P (place): each block bins its 4096 points into (slab, 16x16x128
//     region) bins (aligned float4 entries); block 0 zeroes the global
//     cursors; LDS count -> one global cursor reservation per region.
//   grid.sync()
//   phase A (accum): each block processes 4 bins; region in 128 KiB LDS;
//     LDS atomics; contiguous 8 KB-chunk float4 writeback (no output memset).

#define RES   128
#define GRIDG (RES * RES * RES)
#define NSLAB 16            // 2 clouds * 8 samples
#define NREG  64            // 8*8 xy-regions of 16x16x128 per slab
#define NBIN  (NSLAB * NREG)
#define CAPB  2048          // entries per bin (expected ~1156, >20 sd headroom)
#define CBLK  256           // cooperative blocks (= CUs)
#define CTHR  1024
#define PPB   4096          // points per block in place phase

__device__ __forceinline__ int clampi(int v) {
    return v < 0 ? 0 : (v > RES - 1 ? RES - 1 : v);
}

__global__ __launch_bounds__(1024) void fused_gridding_kernel(
    const float* __restrict__ pred, const float* __restrict__ gt,
    unsigned* __restrict__ cursor,    // [NBIN]
    float4* __restrict__ bins,        // [NBIN][CAPB]
    float* __restrict__ out, int npts)
{
    __shared__ __align__(16) float vox[16 * 16 * 128];   // 128 KiB
    unsigned* cnt  = (unsigned*)vox;          // [NREG]  (place phase only)
    unsigned* curs = (unsigned*)vox + NREG;   // [NREG]

    const int blk  = blockIdx.x;              // 0..255
    const int t    = threadIdx.x;
    const int slab = blk >> 4;                // 16 blocks per slab
    const int chnk = blk & 15;
    const float* cloud = (slab < 8) ? pred : gt;
    const float* cbase = cloud + (size_t)(slab & 7) * npts * 3
                               + (size_t)chnk * PPB * 3;

    // ---- phase P: place ----
    if (t < NREG) cnt[t] = 0;
    if (blk == 0) cursor[t] = 0;              // CTHR == NBIN
    __syncthreads();

    // 4 points per thread via 3 aligned float4 loads
    const float4* b4 = (const float4*)cbase;
    const float4 f0 = b4[3 * t + 0];
    const float4 f1 = b4[3 * t + 1];
    const float4 f2 = b4[3 * t + 2];
    float px[4] = {f0.x, f0.w, f1.z, f2.y};
    float py[4] = {f0.y, f1.x, f1.w, f2.z};
    float pz[4] = {f0.z, f1.y, f2.x, f2.w};
#pragma unroll
    for (int k = 0; k < 4; ++k) {
        px[k] = fmaf(px[k], 128.0f, 64.0f);
        py[k] = fmaf(py[k], 128.0f, 64.0f);
        pz[k] = fmaf(pz[k], 128.0f, 64.0f);
    }

    // count region copies (x/y straddles duplicate; z never splits a region)
#pragma unroll
    for (int k = 0; k < 4; ++k) {
        const int ix = (int)floorf(px[k]), iy = (int)floorf(py[k]);
        const int rx0 = clampi(ix) >> 4, rx1 = clampi(ix + 1) >> 4;
        const int ry0 = clampi(iy) >> 4, ry1 = clampi(iy + 1) >> 4;
        for (int a = rx0; a <= rx1; ++a)
            for (int b = ry0; b <= ry1; ++b)
                atomicAdd(&cnt[(a << 3) | b], 1u);
    }
    __syncthreads();

    cg::this_grid().sync();   // cursor zeroing visible everywhere

    // reserve segment ranges
    if (t < NREG) {
        const unsigned c = cnt[t];
        unsigned base = 0;
        if (c) base = atomicAdd(&cursor[slab * NREG + t], c);
        curs[t] = base;
    }
    __syncthreads();

    // scatter aligned 16B entries
#pragma unroll
    for (int k = 0; k < 4; ++k) {
        const float x = px[k], y = py[k], z = pz[k];
        const int ix = (int)floorf(x), iy = (int)floorf(y);
        const int rx0 = clampi(ix) >> 4, rx1 = clampi(ix + 1) >> 4;
        const int ry0 = clampi(iy) >> 4, ry1 = clampi(iy + 1) >> 4;
        for (int a = rx0; a <= rx1; ++a)
            for (int b = ry0; b <= ry1; ++b) {
                const int r = (a << 3) | b;
                const unsigned slot = atomicAdd(&curs[r], 1u);
                if (slot < CAPB)
                    bins[(size_t)(slab * NREG + r) * CAPB + slot] =
                        make_float4(x, y, z, 0.0f);
            }
    }

    cg::this_grid().sync();   // bins + final cursors visible everywhere

    // ---- phase A: accumulate 4 bins per block ----
    float4* v4 = (float4*)vox;
    for (int q = 0; q < 4; ++q) {
        const int bin   = blk * 4 + q;
        const int aslab = bin >> 6;
        const int reg   = bin & 63;
        const int rx = reg >> 3, ry = reg & 7;

        unsigned n = cursor[bin];
        if (n > CAPB) n = CAPB;

        for (int i = t; i < 8192; i += CTHR) v4[i] = make_float4(0, 0, 0, 0);
        __syncthreads();

        const float4* seg = bins + (size_t)bin * CAPB;
        for (unsigned i = t; i < n; i += CTHR) {
            const float4 e = seg[i];
            const float x = e.x, y = e.y, z = e.z;
            const float xf = floorf(x), yf = floorf(y), zf = floorf(z);
            const float dx = x - xf, dy = y - yf, dz = z - zf;
            const int ix = (int)xf, iy = (int)yf, iz = (int)zf;
            const int x0 = clampi(ix), x1 = clampi(ix + 1);
            const int y0 = clampi(iy), y1 = clampi(iy + 1);
            const int z0 = clampi(iz), z1 = clampi(iz + 1);
            const float wx0 = 1.0f - dx, wy0 = 1.0f - dy, wz0 = 1.0f - dz;

#pragma unroll
            for (int sx = 0; sx < 2; ++sx) {
                const int cx = sx ? x1 : x0;
                if ((cx >> 4) != rx) continue;
                const float wx = sx ? dx : wx0;
#pragma unroll
                for (int sy = 0; sy < 2; ++sy) {
                    const int cy = sy ? y1 : y0;
                    if ((cy >> 4) != ry) continue;
                    const float wxy = wx * (sy ? dy : wy0);
                    const int base = ((cx & 15) << 11) | ((cy & 15) << 7);
                    atomicAdd(&vox[base + z0], wxy * wz0);
                    atomicAdd(&vox[base + z1], wxy * dz);
                }
            }
        }
        __syncthreads();

        // contiguous writeback: 16 chunks (one per local x) of 8 KB
        float* gp = out + (size_t)aslab * GRIDG
                  + ((size_t)rx << 18) + ((size_t)ry << 11);
        for (int v = t; v < 8192; v += CTHR) {
            const int l   = v << 2;        // float index in LDS
            const int lx  = l >> 11;       // local x
            const int rem = l & 2047;      // ly*128+lz, contiguous in global
            *(float4*)(gp + ((size_t)lx << 14) + rem) = v4[v];
        }
        __syncthreads();
    }
}

// ---------------- fallback path (R6 3-node pipeline) ----------------

__global__ __launch_bounds__(256) void place_kernel(
    const float* __restrict__ pred, const float* __restrict__ gt,
    unsigned* __restrict__ cursor, float4* __restrict__ bins,
    int npts, int nblkPerSlab)
{
    __shared__ unsigned cnt[NREG];
    __shared__ unsigned curs[NREG];

    const int gblk = blockIdx.x;
    const int slab = gblk / nblkPerSlab;
    const int blk  = gblk - slab * nblkPerSlab;
    const float* cloud = (slab < 8) ? pred : gt;
    const float* cbase = cloud + (size_t)(slab & 7) * npts * 3 + (size_t)blk * 1024 * 3;

    if (threadIdx.x < NREG) cnt[threadIdx.x] = 0;
    __syncthreads();

    float px[4], py[4], pz[4];
    bool valid[4];
    const int t = threadIdx.x;

#pragma unroll
    for (int k = 0; k < 4; ++k) {
        const int jj = 4 * t + k;
        valid[k] = (blk * 1024 + jj < npts);
        if (valid[k]) {
            px[k] = fmaf(cbase[(size_t)jj * 3 + 0], 128.0f, 64.0f);
            py[k] = fmaf(cbase[(size_t)jj * 3 + 1], 128.0f, 64.0f);
            pz[k] = fmaf(cbase[(size_t)jj * 3 + 2], 128.0f, 64.0f);
        }
    }

#pragma unroll
    for (int k = 0; k < 4; ++k) {
        if (!valid[k]) continue;
        const int ix = (int)floorf(px[k]), iy = (int)floorf(py[k]);
        const int rx0 = clampi(ix) >> 4, rx1 = clampi(ix + 1) >> 4;
        const int ry0 = clampi(iy) >> 4, ry1 = clampi(iy + 1) >> 4;
        for (int a = rx0; a <= rx1; ++a)
            for (int b = ry0; b <= ry1; ++b)
                atomicAdd(&cnt[(a << 3) | b], 1u);
    }
    __syncthreads();

    if (threadIdx.x < NREG) {
        const unsigned c = cnt[threadIdx.x];
        unsigned base = 0;
        if (c) base = atomicAdd(&cursor[slab * NREG + threadIdx.x], c);
        curs[threadIdx.x] = base;
    }
    __syncthreads();

#pragma unroll
    for (int k = 0; k < 4; ++k) {
        if (!valid[k]) continue;
        const float x = px[k], y = py[k], z = pz[k];
        const int ix = (int)floorf(x), iy = (int)floorf(y);
        const int rx0 = clampi(ix) >> 4, rx1 = clampi(ix + 1) >> 4;
        const int ry0 = clampi(iy) >> 4, ry1 = clampi(iy + 1) >> 4;
        for (int a = rx0; a <= rx1; ++a)
            for (int b = ry0; b <= ry1; ++b) {
                const int r = (a << 3) | b;
                const unsigned slot = atomicAdd(&curs[r], 1u);
                if (slot < CAPB)
                    bins[(size_t)(slab * NREG + r) * CAPB + slot] =
                        make_float4(x, y, z, 0.0f);
            }
    }
}

__global__ __launch_bounds__(1024) void accum_kernel(
    const float4* __restrict__ bins, const unsigned* __restrict__ cursor,
    float* __restrict__ out)
{
    __shared__ __align__(16) float vox[16 * 16 * 128];
    const int bin  = blockIdx.x;
    const int slab = bin >> 6;
    const int reg  = bin & 63;
    const int rx = reg >> 3, ry = reg & 7;

    unsigned n = cursor[bin];
    if (n > CAPB) n = CAPB;

    float4* v4 = (float4*)vox;
    for (int i = threadIdx.x; i < 8192; i += 1024) v4[i] = make_float4(0, 0, 0, 0);
    __syncthreads();

    const float4* seg = bins + (size_t)bin * CAPB;
    for (unsigned i = threadIdx.x; i < n; i += 1024) {
        const float4 e = seg[i];
        const float x = e.x, y = e.y, z = e.z;
        const float xf = floorf(x), yf = floorf(y), zf = floorf(z);
        const float dx = x - xf, dy = y - yf, dz = z - zf;
        const int ix = (int)xf, iy = (int)yf, iz = (int)zf;
        const int x0 = clampi(ix), x1 = clampi(ix + 1);
        const int y0 = clampi(iy), y1 = clampi(iy + 1);
        const int z0 = clampi(iz), z1 = clampi(iz + 1);
        const float wx0 = 1.0f - dx, wy0 = 1.0f - dy, wz0 = 1.0f - dz;

#pragma unroll
        for (int sx = 0; sx < 2; ++sx) {
            const int cx = sx ? x1 : x0;
            if ((cx >> 4) != rx) continue;
            const float wx = sx ? dx : wx0;
#pragma unroll
            for (int sy = 0; sy < 2; ++sy) {
                const int cy = sy ? y1 : y0;
                if ((cy >> 4) != ry) continue;
                const float wxy = wx * (sy ? dy : wy0);
                const int base = ((cx & 15) << 11) | ((cy & 15) << 7);
                atomicAdd(&vox[base + z0], wxy * wz0);
                atomicAdd(&vox[base + z1], wxy * dz);
            }
        }
    }
    __syncthreads();

    float* gp = out + (size_t)slab * GRIDG + ((size_t)rx << 18) + ((size_t)ry << 11);
    for (int v = threadIdx.x; v < 8192; v += 1024) {
        const int l   = v << 2;
        const int lx  = l >> 11;
        const int rem = l & 2047;
        *(float4*)(gp + ((size_t)lx << 14) + rem) = v4[v];
    }
}

// ---------------- launcher ----------------

extern "C" void kernel_launch(void* const* d_in, const int* in_sizes, int n_in,
                              void* d_out, int out_size, void* d_ws, size_t ws_size,
                              hipStream_t stream) {
    const float* pred = (const float*)d_in[0];
    const float* gt   = (const float*)d_in[1];
    float* out = (float*)d_out;

    const int bsz  = 8;
    const int npts = in_sizes[0] / (bsz * 3);   // 65536

    const size_t cursorBytes = 4096;
    const size_t binsBytes   = (size_t)NBIN * CAPB * sizeof(float4);
    const size_t needWs      = cursorBytes + binsBytes;      // ~33.6 MB

    unsigned* cursor = (unsigned*)d_ws;
    float4* bins = (float4*)((char*)d_ws + cursorBytes);

    bool done = false;
    if (ws_size >= needWs && npts == CBLK / NSLAB * PPB) {   // 16 blk/slab * 4096
        void* args[] = {(void*)&pred, (void*)&gt, (void*)&cursor,
                        (void*)&bins, (void*)&out, (void*)&npts};
        hipError_t err = hipLaunchCooperativeKernel(
            (const void*)fused_gridding_kernel, dim3(CBLK), dim3(CTHR),
            args, 0, stream);
        done = (err == hipSuccess);
    }

    if (!done && ws_size >= needWs && (npts % 1024) == 0) {
        hipMemsetAsync(cursor, 0, NBIN * sizeof(unsigned), stream);
        const int nblkPerSlab = npts / 1024;
        place_kernel<<<dim3(NSLAB * nblkPerSlab), dim3(256), 0, stream>>>(
            pred, gt, cursor, bins, npts, nblkPerSlab);
        accum_kernel<<<dim3(NBIN), dim3(1024), 0, stream>>>(bins, cursor, out);
        done = true;
    }

    if (!done) {
        // last-resort: global-atomic scatter (R0/R1 measured-correct path)
        hipMemsetAsync(d_out, 0, (size_t)out_size * sizeof(float), stream);
        // reuse accum-free scatter via place-less direct atomics
        // (kept minimal: correctness fallback only)
        struct L {
            static __global__ void sc(const float* __restrict__ cloud,
                                      float* __restrict__ grid, int n) {}
        };
        // direct scatter kernels
        extern __global__ void gridding_scatter_kernel_decl();
        (void)out_size;
        dim3 block(256);
        dim3 grid((npts + 255) / 256, bsz);
        // forward declaration workaround: define below
        void gridding_scatter_launch(const float*, float*, int, dim3, dim3, hipStream_t);
    }
}

// NOTE: the last-resort branch above is unreachable for this problem size
// (ws_size is 512 MiB >> 34 MB and npts == 65536); the two real paths are the
// cooperative fused kernel and the proven 3-node pipeline.

// Round 8
// 188.475 us; speedup vs baseline: 1.3418x; 1.3418x over previous
//
#include <hip/hip_runtime.h>

// GriddingDistance via binning + LDS privatization (8x8x128 regions).
// Output: [pred_grid (8*G) | gt_grid (8*G)] fp32, G = 128^3.
//
// 3-node pipeline (cooperative fusion measured WORSE in R7 — 1 block/CU
// starved the place phase and serialized accum phases):
//   1. hipMemsetAsync: zero 4096 bin cursors (16 KB).
//   2. place_kernel: bin points into (slab, 8x8x128 region) bins as aligned
//      float4; points straddling x/y region boundaries duplicate (avg ~1.27).
//   3. accum_kernel: one 256-thread block per bin; region in 32 KiB LDS
//      (5 blocks/CU resident -> phases of different bins overlap); LDS
//      atomics; contiguous 4 KB-chunk float4 writeback (no output memset).

#define RES   128
#define GRIDG (RES * RES * RES)
#define NSLAB 16            // 2 clouds * 8 samples
#define NRX   16            // regions per x/y axis (region = 8x8x128)
#define NREG  256           // regions per slab
#define NBIN  (NSLAB * NREG)  // 4096
#define CAPB  640           // entries per bin (expected ~324, sd ~18)
#define PTS_PER_BLOCK 1024

__device__ __forceinline__ int clampi(int v) {
    return v < 0 ? 0 : (v > RES - 1 ? RES - 1 : v);
}

// ---------------- place ----------------

__global__ __launch_bounds__(256) void place_kernel(
    const float* __restrict__ pred, const float* __restrict__ gt,
    unsigned* __restrict__ cursor,    // [NBIN]
    float4* __restrict__ bins,        // [NBIN][CAPB]
    int npts, int nblkPerSlab)
{
    __shared__ unsigned cnt[NREG];
    __shared__ unsigned curs[NREG];

    const int gblk = blockIdx.x;
    const int slab = gblk / nblkPerSlab;
    const int blk  = gblk - slab * nblkPerSlab;
    const float* cloud = (slab < 8) ? pred : gt;
    const float* cbase = cloud + (size_t)(slab & 7) * npts * 3
                               + (size_t)blk * PTS_PER_BLOCK * 3;

    const int t = threadIdx.x;
    cnt[t] = 0;                       // NREG == blockDim == 256
    __syncthreads();

    float px[4], py[4], pz[4];
    bool valid[4];
    const bool fullBlock = ((blk + 1) * PTS_PER_BLOCK) <= npts;

    if (fullBlock) {
        const float4* b4 = (const float4*)cbase;
        const float4 f0 = b4[3 * t + 0];
        const float4 f1 = b4[3 * t + 1];
        const float4 f2 = b4[3 * t + 2];
        px[0] = f0.x; py[0] = f0.y; pz[0] = f0.z;
        px[1] = f0.w; py[1] = f1.x; pz[1] = f1.y;
        px[2] = f1.z; py[2] = f1.w; pz[2] = f2.x;
        px[3] = f2.y; py[3] = f2.z; pz[3] = f2.w;
#pragma unroll
        for (int k = 0; k < 4; ++k) {
            valid[k] = true;
            px[k] = fmaf(px[k], 128.0f, 64.0f);
            py[k] = fmaf(py[k], 128.0f, 64.0f);
            pz[k] = fmaf(pz[k], 128.0f, 64.0f);
        }
    } else {
#pragma unroll
        for (int k = 0; k < 4; ++k) {
            const int jj = 4 * t + k;
            valid[k] = (blk * PTS_PER_BLOCK + jj < npts);
            if (valid[k]) {
                px[k] = fmaf(cbase[(size_t)jj * 3 + 0], 128.0f, 64.0f);
                py[k] = fmaf(cbase[(size_t)jj * 3 + 1], 128.0f, 64.0f);
                pz[k] = fmaf(cbase[(size_t)jj * 3 + 2], 128.0f, 64.0f);
            }
        }
    }

    // count region copies (x/y straddles duplicate; z never splits a region)
#pragma unroll
    for (int k = 0; k < 4; ++k) {
        if (!valid[k]) continue;
        const int ix = (int)floorf(px[k]), iy = (int)floorf(py[k]);
        const int rx0 = clampi(ix) >> 3, rx1 = clampi(ix + 1) >> 3;
        const int ry0 = clampi(iy) >> 3, ry1 = clampi(iy + 1) >> 3;
        for (int a = rx0; a <= rx1; ++a)
            for (int b = ry0; b <= ry1; ++b)
                atomicAdd(&cnt[(a << 4) | b], 1u);
    }
    __syncthreads();

    // reserve segment ranges; curs[] = running within-segment cursor
    {
        const unsigned c = cnt[t];
        unsigned base = 0;
        if (c) base = atomicAdd(&cursor[slab * NREG + t], c);
        curs[t] = base;
    }
    __syncthreads();

    // scatter aligned 16B entries
#pragma unroll
    for (int k = 0; k < 4; ++k) {
        if (!valid[k]) continue;
        const float x = px[k], y = py[k], z = pz[k];
        const int ix = (int)floorf(x), iy = (int)floorf(y);
        const int rx0 = clampi(ix) >> 3, rx1 = clampi(ix + 1) >> 3;
        const int ry0 = clampi(iy) >> 3, ry1 = clampi(iy + 1) >> 3;
        for (int a = rx0; a <= rx1; ++a)
            for (int b = ry0; b <= ry1; ++b) {
                const int r = (a << 4) | b;
                const unsigned slot = atomicAdd(&curs[r], 1u);
                if (slot < CAPB)
                    bins[(size_t)(slab * NREG + r) * CAPB + slot] =
                        make_float4(x, y, z, 0.0f);
            }
    }
}

// ---------------- accumulate ----------------

__global__ __launch_bounds__(256) void accum_kernel(
    const float4* __restrict__ bins, const unsigned* __restrict__ cursor,
    float* __restrict__ out)
{
    __shared__ __align__(16) float vox[8 * 8 * 128];   // 32 KiB

    const int bin  = blockIdx.x;            // 0..NBIN-1
    const int slab = bin >> 8;
    const int reg  = bin & 255;
    const int rx = reg >> 4, ry = reg & 15;

    unsigned n = cursor[bin];
    if (n > CAPB) n = CAPB;

    float4* v4 = (float4*)vox;
    for (int i = threadIdx.x; i < 2048; i += 256) v4[i] = make_float4(0, 0, 0, 0);
    __syncthreads();

    const float4* seg = bins + (size_t)bin * CAPB;
    for (unsigned i = threadIdx.x; i < n; i += 256) {
        const float4 e = seg[i];
        const float x = e.x, y = e.y, z = e.z;
        const float xf = floorf(x), yf = floorf(y), zf = floorf(z);
        const float dx = x - xf, dy = y - yf, dz = z - zf;
        const int ix = (int)xf, iy = (int)yf, iz = (int)zf;
        const int x0 = clampi(ix), x1 = clampi(ix + 1);
        const int y0 = clampi(iy), y1 = clampi(iy + 1);
        const int z0 = clampi(iz), z1 = clampi(iz + 1);
        const float wx0 = 1.0f - dx, wy0 = 1.0f - dy, wz0 = 1.0f - dz;

#pragma unroll
        for (int sx = 0; sx < 2; ++sx) {
            const int cx = sx ? x1 : x0;
            if ((cx >> 3) != rx) continue;
            const float wx = sx ? dx : wx0;
#pragma unroll
            for (int sy = 0; sy < 2; ++sy) {
                const int cy = sy ? y1 : y0;
                if ((cy >> 3) != ry) continue;
                const float wxy = wx * (sy ? dy : wy0);
                const int base = ((cx & 7) << 10) | ((cy & 7) << 7);
                atomicAdd(&vox[base + z0], wxy * wz0);
                atomicAdd(&vox[base + z1], wxy * dz);
            }
        }
    }
    __syncthreads();

    // contiguous writeback: 8 chunks (one per local x) of 4 KB
    float* gp = out + (size_t)slab * GRIDG
              + ((size_t)rx << 17) + ((size_t)ry << 10);
    for (int v = threadIdx.x; v < 2048; v += 256) {
        const int l   = v << 2;        // float index in LDS
        const int lx  = l >> 10;       // local x (0..7)
        const int rem = l & 1023;      // ly*128+lz, contiguous in global
        *(float4*)(gp + ((size_t)lx << 14) + rem) = v4[v];
    }
}

// ---------------- fallback (R1 measured-correct atomic scatter) ----------------

__global__ __launch_bounds__(256) void gridding_scatter_kernel(
    const float* __restrict__ cloud, float* __restrict__ grid, int n)
{
    const int j = blockIdx.x * blockDim.x + threadIdx.x;
    if (j >= n) return;
    const int b = blockIdx.y;
    const size_t pt = (size_t)b * n + j;

    const float x = fmaf(cloud[pt * 3 + 0], 128.0f, 64.0f);
    const float y = fmaf(cloud[pt * 3 + 1], 128.0f, 64.0f);
    const float z = fmaf(cloud[pt * 3 + 2], 128.0f, 64.0f);
    const float xf = floorf(x), yf = floorf(y), zf = floorf(z);
    const float dx = x - xf, dy = y - yf, dz = z - zf;
    const int ix = (int)xf, iy = (int)yf, iz = (int)zf;
    const int x0 = clampi(ix), x1 = clampi(ix + 1);
    const int y0 = clampi(iy), y1 = clampi(iy + 1);
    const int z0 = clampi(iz), z1 = clampi(iz + 1);
    const float wx0 = 1.0f - dx, wy0 = 1.0f - dy, wz0 = 1.0f - dz;

    float* gp = grid + (size_t)b * GRIDG;
    const int bx0 = x0 << 14, bx1 = x1 << 14;
    const int by0 = y0 << 7,  by1 = y1 << 7;
    atomicAdd(gp + (bx0 + by0 + z0), wx0 * wy0 * wz0);
    atomicAdd(gp + (bx0 + by0 + z1), wx0 * wy0 * dz);
    atomicAdd(gp + (bx0 + by1 + z0), wx0 * dy * wz0);
    atomicAdd(gp + (bx0 + by1 + z1), wx0 * dy * dz);
    atomicAdd(gp + (bx1 + by0 + z0), dx * wy0 * wz0);
    atomicAdd(gp + (bx1 + by0 + z1), dx * wy0 * dz);
    atomicAdd(gp + (bx1 + by1 + z0), dx * dy * wz0);
    atomicAdd(gp + (bx1 + by1 + z1), dx * dy * dz);
}

// ---------------- launcher ----------------

extern "C" void kernel_launch(void* const* d_in, const int* in_sizes, int n_in,
                              void* d_out, int out_size, void* d_ws, size_t ws_size,
                              hipStream_t stream) {
    const float* pred = (const float*)d_in[0];
    const float* gt   = (const float*)d_in[1];
    float* out = (float*)d_out;

    const int bsz  = 8;
    const int npts = in_sizes[0] / (bsz * 3);   // 65536

    const size_t cursorBytes = (size_t)NBIN * sizeof(unsigned);      // 16 KB
    const size_t binsBytes   = (size_t)NBIN * CAPB * sizeof(float4); // ~41.9 MB
    const size_t needWs      = cursorBytes + binsBytes;

    if (ws_size >= needWs) {
        unsigned* cursor = (unsigned*)d_ws;
        float4* bins = (float4*)((char*)d_ws + cursorBytes);

        hipMemsetAsync(cursor, 0, cursorBytes, stream);

        const int nblkPerSlab = (npts + PTS_PER_BLOCK - 1) / PTS_PER_BLOCK; // 64
        place_kernel<<<dim3(NSLAB * nblkPerSlab), dim3(256), 0, stream>>>(
            pred, gt, cursor, bins, npts, nblkPerSlab);
        accum_kernel<<<dim3(NBIN), dim3(256), 0, stream>>>(bins, cursor, out);
    } else {
        // fallback: global-atomic scatter
        hipMemsetAsync(d_out, 0, (size_t)out_size * sizeof(float), stream);
        dim3 block(256);
        dim3 grid((npts + 255) / 256, bsz);
        float* pred_grid = out;
        float* gt_grid   = out + (size_t)bsz * GRIDG;
        gridding_scatter_kernel<<<grid, block, 0, stream>>>(pred, pred_grid, npts);
        gridding_scatter_kernel<<<grid, block, 0, stream>>>(gt,   gt_grid,   npts);
    }
}